// Round 5
// baseline (318.507 us; speedup 1.0000x reference)
//
#include <hip/hip_runtime.h>

// Problem constants
#define BB 4
#define CC 256
#define TT 8
#define HH 16
#define WW 16
#define LL 8
#define NO 8
#define DD 32
#define BT 32          // B*T
#define VV 2048        // H*W*L
#define KIN 512        // feat+pos channels for GEMM
#define EPS_ 1e-5f

typedef short bf16x8 __attribute__((ext_vector_type(8)));
typedef float f32x4 __attribute__((ext_vector_type(4)));
typedef float f32x2 __attribute__((ext_vector_type(2)));

static __device__ __forceinline__ float b2f(unsigned short u) {
    return __uint_as_float(((unsigned int)u) << 16);
}
static __device__ __forceinline__ float b2f_lo(unsigned int x) {
    return __uint_as_float(x << 16);
}
static __device__ __forceinline__ float b2f_hi(unsigned int x) {
    return __uint_as_float(x & 0xffff0000u);
}
static __device__ __forceinline__ unsigned short f2b(float f) {
    unsigned int x = __float_as_uint(f);
    unsigned int r = x + 0x7fffu + ((x >> 16) & 1u);   // RNE (finite values)
    return (unsigned short)(r >> 16);
}
static __device__ __forceinline__ unsigned int f2b_pk(float lo, float hi) {
    return (unsigned int)f2b(lo) | ((unsigned int)f2b(hi) << 16);
}
static __device__ __forceinline__ float sigm(float x) {
    return 1.0f / (1.0f + __expf(-x));
}
// async global->LDS, 16B per lane; LDS dest = wave-uniform base + lane*16
static __device__ __forceinline__ void glds16(const void* g, void* l) {
    __builtin_amdgcn_global_load_lds(
        (const __attribute__((address_space(1))) void*)g,
        (__attribute__((address_space(3))) void*)l, 16, 0, 0);
}
// lane-xor exchange routed off the DS pipe where possible:
// j=1,2 quad_perm DPP; j=8 row_ror:8 (==xor8 within 16); j=4,16 ds_swizzle; j=32 bpermute
static __device__ __forceinline__ int xsw(int x, int j) {
    switch (j) {
        case 1:  return __builtin_amdgcn_update_dpp(0, x, 0xB1, 0xF, 0xF, true);
        case 2:  return __builtin_amdgcn_update_dpp(0, x, 0x4E, 0xF, 0xF, true);
        case 8:  return __builtin_amdgcn_update_dpp(0, x, 0x128, 0xF, 0xF, true);
        case 4:  return __builtin_amdgcn_ds_swizzle(x, 0x101F);
        case 16: return __builtin_amdgcn_ds_swizzle(x, 0x401F);
        default: return __shfl_xor(x, 32);
    }
}

// ---------------------------------------------------------------------------
// K0: convert Wp[:, 0:512] -> bf16 A-matrix
// ---------------------------------------------------------------------------
__global__ __launch_bounds__(256) void k0_prep(const float* __restrict__ Wp,
                                               unsigned short* __restrict__ Wa) {
    int i = blockIdx.x * 256 + threadIdx.x;
    int o = i >> 9, k = i & 511;
    Wa[i] = f2b(Wp[o * 768 + k]);
}

// ---------------------------------------------------------------------------
// K1: streaming transpose feat/pos (B,C,T,v) -> srcT bf16 [n][v][512]
//     (unchanged from round-4 passing version)
// ---------------------------------------------------------------------------
__global__ __launch_bounds__(256) void k1_transpose(const float* __restrict__ features,
                                                    const float* __restrict__ pos,
                                                    unsigned short* __restrict__ srcT,
                                                    float* __restrict__ gpart) {
    const int vt  = blockIdx.x;         // 0..15 (128-v tile)
    const int ch  = blockIdx.y & 1;     // channel half 0..1
    const int arr = blockIdx.y >> 1;    // 0 = feat, 1 = pos
    const int n   = blockIdx.z;         // 0..31
    const int v0 = vt * 128;
    const int b = n >> 3, t = n & 7;
    const int tid = threadIdx.x;
    const int w = tid >> 6;             // wave 0..3 -> c range [w*32, w*32+32)
    const int lane = tid & 63;
    const int v16 = lane >> 2;          // 0..15 -> v group v16*4 (low half)
    const int cs  = lane & 3;           // 0..3

    __shared__ uint2 sg[128 * 33];      // granule g = v*33 + cq

    const float* src = arr ? pos : features;
    const size_t cb = ((size_t)(b * CC + ch * 128 + w * 32) * TT + t) * (size_t)VV
                      + v0 + v16 * 4;

    // 16 float4 loads in flight; per channel: vh=0 then vh=1 (+256B adjacent)
    float4 f[2][4][2];                  // [i][e][vh]
    #pragma unroll
    for (int i = 0; i < 2; ++i)
        #pragma unroll
        for (int e = 0; e < 4; ++e)
            #pragma unroll
            for (int vh = 0; vh < 2; ++vh)
                f[i][e][vh] = *(const float4*)(src + cb
                                + (size_t)(i * 16 + cs * 4 + e) * (TT * VV) + vh * 64);

    // pack channel quad -> uint2 (bf16 x4) per v, ds_write_b64 (conflict-free)
    #pragma unroll
    for (int i = 0; i < 2; ++i) {
        const int cq = w * 8 + i * 4 + cs;
        #pragma unroll
        for (int vh = 0; vh < 2; ++vh) {
            #pragma unroll
            for (int k = 0; k < 4; ++k) {
                const int v = vh * 64 + v16 * 4 + k;
                uint2 u;
                u.x = f2b_pk(((const float*)&f[i][0][vh])[k], ((const float*)&f[i][1][vh])[k]);
                u.y = f2b_pk(((const float*)&f[i][2][vh])[k], ((const float*)&f[i][3][vh])[k]);
                sg[v * 33 + cq] = u;
            }
        }
    }

    // fused per-channel feat sums (gpart) from registers: sum over 128 v
    if (arr == 0) {
        float part[2][4];
        #pragma unroll
        for (int i = 0; i < 2; ++i)
            #pragma unroll
            for (int e = 0; e < 4; ++e) {
                part[i][e] = f[i][e][0].x + f[i][e][0].y + f[i][e][0].z + f[i][e][0].w
                           + f[i][e][1].x + f[i][e][1].y + f[i][e][1].z + f[i][e][1].w;
                #pragma unroll
                for (int m = 4; m < 64; m <<= 1)
                    part[i][e] += __shfl_xor(part[i][e], m);
            }
        if (lane < 4) {   // v16 == 0, cs = lane
            float* gp = gpart + ((size_t)n * 16 + vt) * CC + ch * 128 + w * 32 + cs * 4;
            *(float4*)gp        = make_float4(part[0][0], part[0][1], part[0][2], part[0][3]);
            *(float4*)(gp + 16) = make_float4(part[1][0], part[1][1], part[1][2], part[1][3]);
        }
    }
    __syncthreads();

    // write-out: row v, 128 bf16 channels; 2x ds_read_b64 -> uint4 store (16B/lane)
    const int vh2 = tid >> 4;           // 0..15
    const int q   = tid & 15;           // 0..15 -> channels q*8..q*8+7
    unsigned short* ob = srcT + ((size_t)n * VV + v0) * KIN + arr * 256 + ch * 128 + q * 8;
    #pragma unroll
    for (int j = 0; j < 8; ++j) {
        const int v = j * 16 + vh2;
        uint2 lo = sg[v * 33 + q * 2];
        uint2 hi = sg[v * 33 + q * 2 + 1];
        uint4 o;
        o.x = lo.x; o.y = lo.y; o.z = hi.x; o.w = hi.y;
        *(uint4*)(ob + (size_t)v * KIN) = o;
    }
}

// ---------------------------------------------------------------------------
// K2: reduce gpart -> glob mean; gterm[n][o] = bp[o] + sum_c Wp[o][512+c]*mean[n][c]
// ---------------------------------------------------------------------------
__global__ __launch_bounds__(256) void k2_gterm(const float* __restrict__ gpart,
                                                const float* __restrict__ Wp,
                                                const float* __restrict__ bp,
                                                float* __restrict__ gterm) {
    const int n = blockIdx.x;
    const int o = threadIdx.x;          // channel index, then output index
    __shared__ float gl[CC];
    float s = 0.0f;
    const float* gp = gpart + (size_t)n * 16 * CC + o;
    #pragma unroll 8
    for (int vt = 0; vt < 16; ++vt) s += gp[vt * CC];
    gl[o] = s * (1.0f / (float)VV);
    __syncthreads();
    const float4* wrow = (const float4*)(Wp + (size_t)o * 768 + 512);
    const float4* g4 = (const float4*)gl;
    float acc = bp[o];
    #pragma unroll 8
    for (int c = 0; c < 64; ++c) {
        float4 w = wrow[c], g = g4[c];
        acc += w.x * g.x + w.y * g.y + w.z * g.z + w.w * g.w;
    }
    gterm[n * CC + o] = acc;
}

// ---------------------------------------------------------------------------
// K3: GEMM  projT[n][v][o] = relu( sum_k Wa[o][k]*srcT[n][v][k] + gterm[n][o] )
//     128x128 tile, 4 waves (2x2 of 64x64), 16x16x32 bf16 MFMA, BK=32.
//     m97 structure: global_load_lds(16B) into linear LDS (stride 32 shorts).
// ---------------------------------------------------------------------------
__global__ __launch_bounds__(256) void k3_gemm(const unsigned short* __restrict__ Wa,
                                               const unsigned short* __restrict__ srcT,
                                               const float* __restrict__ gterm,
                                               unsigned short* __restrict__ projT) {
    const int n  = blockIdx.x;   // batch 0..31
    const int mb = blockIdx.y;   // 0..1   (o block)
    const int nb = blockIdx.z;   // 0..15  (v block)
    const int tid = threadIdx.x;
    const int m0 = mb * 128, v0 = nb * 128;

    __shared__ short As[128 * 32];   // linear [row][k], 64B rows
    __shared__ short Bs[128 * 32];

    const int w = tid >> 6;
    const int lane = tid & 63;
    const int wm = w >> 1, wn = w & 1;
    const int lr = lane & 15, lq = lane >> 4;

    f32x4 acc[4][4];
    #pragma unroll
    for (int i = 0; i < 4; ++i)
        #pragma unroll
        for (int j = 0; j < 4; ++j)
            acc[i][j] = (f32x4){0.f, 0.f, 0.f, 0.f};

    const int rsub = lane >> 2;          // 0..15
    const int ksub = (lane & 3) * 8;     // shorts
    const unsigned short* agp = Wa   + (size_t)(m0 + w * 16 + rsub) * KIN + ksub;
    const unsigned short* bgp = srcT + ((size_t)n * VV + v0 + w * 16 + rsub) * KIN + ksub;
    short* alds0 = &As[(w * 16) * 32];        // wave-uniform bases
    short* alds1 = &As[(64 + w * 16) * 32];
    short* blds0 = &Bs[(w * 16) * 32];
    short* blds1 = &Bs[(64 + w * 16) * 32];

    for (int k0 = 0; k0 < KIN; k0 += 32) {
        __syncthreads();                       // prev tile fully consumed
        glds16(agp + k0,                    alds0);
        glds16(agp + k0 + (size_t)64 * KIN, alds1);
        glds16(bgp + k0,                    blds0);
        glds16(bgp + k0 + (size_t)64 * KIN, blds1);
        __syncthreads();                       // vmcnt drained -> tiles ready

        bf16x8 af[4], bf[4];
        #pragma unroll
        for (int i = 0; i < 4; ++i)
            af[i] = *(const bf16x8*)&As[(wm * 64 + i * 16 + lr) * 32 + lq * 8];
        #pragma unroll
        for (int j = 0; j < 4; ++j)
            bf[j] = *(const bf16x8*)&Bs[(wn * 64 + j * 16 + lr) * 32 + lq * 8];
        #pragma unroll
        for (int i = 0; i < 4; ++i)
            #pragma unroll
            for (int j = 0; j < 4; ++j)
                acc[i][j] = __builtin_amdgcn_mfma_f32_16x16x32_bf16(af[i], bf[j], acc[i][j], 0, 0, 0);
    }

    // epilogue: C/D layout col=lane&15 (v), row=(lane>>4)*4+r (o)
    #pragma unroll
    for (int i = 0; i < 4; ++i) {
        const int og = m0 + wm * 64 + i * 16 + lq * 4;
        float4 g = *(const float4*)(gterm + n * CC + og);
        #pragma unroll
        for (int j = 0; j < 4; ++j) {
            const int vg = v0 + wn * 64 + j * 16 + lr;
            float x0 = fmaxf(acc[i][j][0] + g.x, 0.0f);
            float x1 = fmaxf(acc[i][j][1] + g.y, 0.0f);
            float x2 = fmaxf(acc[i][j][2] + g.z, 0.0f);
            float x3 = fmaxf(acc[i][j][3] + g.w, 0.0f);
            ushort4 st;
            st.x = f2b(x0); st.y = f2b(x1); st.z = f2b(x2); st.w = f2b(x3);
            *(ushort4*)&projT[((size_t)n * VV + vg) * CC + og] = st;
        }
    }
}

// ---------------------------------------------------------------------------
// K5 (fused K4+K5): per voxel, one wave.
//     Front-end: lane = head*8 + corner. Octet (8 lanes) computes one head's
//     offset/weight MLP from projT (8B/lane, wave reads one 512B row,
//     xor-reduce over octet), then each lane evaluates ITS corner -> (lin,w).
//     Back-end: bitonic dedup sort + segmented sum + compact + readlane gather
//     (unchanged from round-3 passing version).
//     res overlays projT: each wave reads exactly the row it overwrites. Safe.
// ---------------------------------------------------------------------------
__global__ __launch_bounds__(256) void k5_fused(const unsigned short* __restrict__ projT,
                                                const unsigned short* __restrict__ srcT,
                                                const float* __restrict__ Wo,
                                                const float* __restrict__ bo,
                                                const float* __restrict__ Ww,
                                                const float* __restrict__ bw,
                                                unsigned short* __restrict__ res) {
    __shared__ float sWo[96], sWd[32], sb[5];
    __shared__ int   sK[4 * 64];
    __shared__ float sW[4 * 64];
    const int tid = threadIdx.x;
    const int wid = tid >> 6;
    const int lane = tid & 63;
    if (tid < 96) sWo[tid] = Wo[tid];
    if (tid < 32) sWd[tid] = Ww[2 * tid + 1] - Ww[2 * tid];
    if (tid < 3)  sb[tid] = bo[tid];
    if (tid < 2)  sb[3 + tid] = bw[tid];
    __syncthreads();

    const int gv = blockIdx.x * 4 + wid;      // global voxel slot 0..65535
    const int n = gv >> 11;
    const int v = gv & 2047;

    // ---- fused K4 front-end ----
    const int hd = lane >> 3;                 // head 0..7
    const int s  = lane & 7;                  // corner 0..7 (dz=s>>2,dy=(s>>1)&1,dx=s&1)

    // lane reads 4 channels (8B); wave covers the full 512B projT row
    uint2 pr = *(const uint2*)(projT + ((size_t)n * VV + v) * CC + lane * 4);
    float t0 = b2f_lo(pr.x), t1 = b2f_hi(pr.x), t2 = b2f_lo(pr.y), t3 = b2f_hi(pr.y);
    const int d0 = s * 4;                     // channel-in-head of t0
    float o0 = t0 * sWo[3 * d0 + 0] + t1 * sWo[3 * d0 + 3] + t2 * sWo[3 * d0 + 6] + t3 * sWo[3 * d0 + 9];
    float o1 = t0 * sWo[3 * d0 + 1] + t1 * sWo[3 * d0 + 4] + t2 * sWo[3 * d0 + 7] + t3 * sWo[3 * d0 + 10];
    float o2 = t0 * sWo[3 * d0 + 2] + t1 * sWo[3 * d0 + 5] + t2 * sWo[3 * d0 + 8] + t3 * sWo[3 * d0 + 11];
    float zw = t0 * sWd[d0] + t1 * sWd[d0 + 1] + t2 * sWd[d0 + 2] + t3 * sWd[d0 + 3];
    // octet xor-reduce (lanes hd*8..hd*8+7)
    #pragma unroll
    for (int m = 1; m < 8; m <<= 1) {
        o0 += __shfl_xor(o0, m);
        o1 += __shfl_xor(o1, m);
        o2 += __shfl_xor(o2, m);
        zw += __shfl_xor(zw, m);
    }
    o0 += sb[0]; o1 += sb[1]; o2 += sb[2];
    const float wgt = sigm(zw + sb[4] - sb[3]);   // softmax(...)[...,1]

    const int h = v >> 7, wv_ = (v >> 3) & 15, l = v & 7;
    float ph = fminf(fmaxf(h   * (1.0f / 15.0f), EPS_), 1.0f - EPS_);
    float pw = fminf(fmaxf(wv_ * (1.0f / 15.0f), EPS_), 1.0f - EPS_);
    float pl = fminf(fmaxf(l   * (1.0f / 7.0f),  EPS_), 1.0f - EPS_);
    float sph = sigm(__logf(ph / (1.0f - ph)) + sigm(o0));
    float spw = sigm(__logf(pw / (1.0f - pw)) + sigm(o1));
    float spl = sigm(__logf(pl / (1.0f - pl)) + sigm(o2));
    float pixh = sph * 16.0f - 0.5f;
    float pixw = spw * 16.0f - 0.5f;
    float pixl = spl * 8.0f  - 0.5f;
    float flh = floorf(pixh), flw = floorf(pixw), fll = floorf(pixl);
    float fh = pixh - flh, fw = pixw - flw, fl = pixl - fll;
    const int dz = s >> 2, dy = (s >> 1) & 1, dx = s & 1;
    int iz = (int)flh + dz, iy = (int)flw + dy, ix = (int)fll + dx;
    float wt = (dz ? fh : 1.0f - fh) * (dy ? fw : 1.0f - fw) * (dx ? fl : 1.0f - fl) * wgt;
    bool valid = ((unsigned)iz < 16u) && ((unsigned)iy < 16u) && ((unsigned)ix < 8u);
    int key = valid ? (((iz * 16 + iy) * 8 + ix) << 10) : 0;   // row BYTE offset
    float w = valid ? wt : 0.0f;

    // ---- dedup back-end (unchanged) ----
    // bitonic sort 64 lanes by key (ascending); exchanges off DS pipe where possible
    #pragma unroll
    for (int k = 2; k <= 64; k <<= 1) {
        #pragma unroll
        for (int j = k >> 1; j > 0; j >>= 1) {
            int pk = xsw(key, j);
            float pw2 = __int_as_float(xsw(__float_as_int(w), j));
            bool keepMin = (((lane & k) == 0) == ((lane & j) == 0));
            bool take = keepMin ? (pk < key) : (pk > key);
            if (take) { key = pk; w = pw2; }
        }
    }
    // segmented inclusive sum of w over equal-key runs
    #pragma unroll
    for (int d = 1; d < 64; d <<= 1) {
        float tw = __shfl_up(w, d);
        int   tk = __shfl_up(key, d);
        if (lane >= d && tk == key) w += tw;
    }
    int nk = __shfl_down(key, 1);
    bool tail = (lane == 63) || (nk != key);  // last lane of each run holds run total
    unsigned long long mask = __ballot(tail);
    int cnt = __popcll(mask);
    int cidx = __popcll(mask & ((1ull << lane) - 1ull));

    // compact unique (key, total w) into per-wave LDS; barriers are load-bearing
    sK[wid * 64 + lane] = 0;
    sW[wid * 64 + lane] = 0.0f;
    __syncthreads();
    if (tail) { sK[wid * 64 + cidx] = key; sW[wid * 64 + cidx] = w; }
    __syncthreads();
    int ck = sK[wid * 64 + lane];
    float cw = sW[wid * 64 + lane];

    // gather unique rows: 64 lanes x 8B (4 channels each), 8 loads in flight
    const char* slabB = (const char*)srcT + (size_t)n * VV * KIN * 2 + lane * 8;
    f32x2 a01 = (f32x2){0.f, 0.f}, a23 = (f32x2){0.f, 0.f};
    const int iters = (cnt + 7) & ~7;
    #pragma unroll 1
    for (int e = 0; e < iters; e += 8) {
        uint2 f[8]; float wvv[8];
        #pragma unroll
        for (int u = 0; u < 8; ++u) {
            int rk = __builtin_amdgcn_readlane(ck, e + u);            // SGPR, no DS
            wvv[u] = __uint_as_float(
                        __builtin_amdgcn_readlane(__float_as_uint(cw), e + u));
            f[u] = *(const uint2*)(slabB + (unsigned)rk);
        }
        #pragma unroll
        for (int u = 0; u < 8; ++u) {
            a01 += wvv[u] * (f32x2){b2f_lo(f[u].x), b2f_hi(f[u].x)};  // v_pk_fma_f32
            a23 += wvv[u] * (f32x2){b2f_lo(f[u].y), b2f_hi(f[u].y)};
        }
    }

    uint2 st;
    st.x = f2b_pk(a01.x, a01.y);
    st.y = f2b_pk(a23.x, a23.y);
    *(uint2*)&res[((size_t)n * VV + v) * CC + lane * 4] = st;
}

// ---------------------------------------------------------------------------
// K6: out[b][c][t][v] = features[b][c][t][v] + res[n][v][c]   (LDS transpose)
//     c-tile 128: res reads as uint2 -> 256B segments.
// ---------------------------------------------------------------------------
__global__ __launch_bounds__(256) void k6_final(const float* __restrict__ features,
                                                const unsigned short* __restrict__ res,
                                                float* __restrict__ out) {
    const int n = blockIdx.x;            // 0..31
    const int c0 = blockIdx.y * 128;     // 0..1 -> c tile
    const int v0 = blockIdx.z * 64;      // 0..31 -> v tile
    const int b = n >> 3, t = n & 7;
    const int tid = threadIdx.x;

    __shared__ uint2 t6[64 * 33];        // [v][c-quad], pad 1

    // load: 8 passes x (8 rows x 32 uint2 = 128c)
    const int lr = tid >> 5;             // 0..7 row-sub
    const int cp = tid & 31;             // c-quad
    #pragma unroll
    for (int p = 0; p < 8; ++p) {
        const int r = p * 8 + lr;
        t6[r * 33 + cp] = *(const uint2*)&res[((size_t)n * VV + v0 + r) * CC + c0 + cp * 4];
    }
    __syncthreads();

    const unsigned short* t6s = (const unsigned short*)t6;
    const int tx = tid & 63;             // v within tile
    const int cl0 = tid >> 6;            // 0..3
    #pragma unroll 8
    for (int p = 0; p < 32; ++p) {
        const int cl = p * 4 + cl0;
        const int c = c0 + cl;
        size_t oidx = (((size_t)b * CC + c) * TT + t) * VV + v0 + tx;
        unsigned short val = t6s[(tx * 33 + (cl >> 2)) * 4 + (cl & 3)];
        out[oidx] = features[oidx] + b2f(val);
    }
}

// ---------------------------------------------------------------------------
extern "C" void kernel_launch(void* const* d_in, const int* in_sizes, int n_in,
                              void* d_out, int out_size, void* d_ws, size_t ws_size,
                              hipStream_t stream) {
    (void)in_sizes; (void)n_in; (void)out_size; (void)ws_size;
    const float* features = (const float*)d_in[0];
    const float* pos      = (const float*)d_in[1];
    const float* Wp       = (const float*)d_in[2];
    const float* bp       = (const float*)d_in[3];
    const float* Wo       = (const float*)d_in[4];
    const float* bo       = (const float*)d_in[5];
    const float* Ww       = (const float*)d_in[6];
    const float* bw       = (const float*)d_in[7];
    float* out = (float*)d_out;

    char* ws = (char*)d_ws;
    unsigned short* srcT  = (unsigned short*)ws;                   // 64 MiB: [32][2048][512] bf16
    unsigned short* Wa    = (unsigned short*)(ws + 67108864);      // 256 KiB
    float*          gterm = (float*)(ws + 67403776);               // 32 KiB
    unsigned short* projT = (unsigned short*)(ws + 67436544);      // 32 MiB: [32][2048][256] bf16
    float*          gpart = (float*)(ws + 100990976);              // 512 KiB: [32][16][256] f32
    unsigned short* res   = projT;                                 // overlay: each k5 wave reads
                                                                   // its projT row before overwriting

    k0_prep<<<512, 256, 0, stream>>>(Wp, Wa);
    k1_transpose<<<dim3(16, 4, 32), 256, 0, stream>>>(features, pos, srcT, gpart);
    k2_gterm<<<32, 256, 0, stream>>>(gpart, Wp, bp, gterm);
    k3_gemm<<<dim3(32, 2, 16), 256, 0, stream>>>(Wa, srcT, gterm, projT);
    k5_fused<<<16384, 256, 0, stream>>>(projT, srcT, Wo, bo, Ww, bw, res);
    k6_final<<<dim3(32, 2, 32), 256, 0, stream>>>(features, res, out);
}

// Round 7
// 312.777 us; speedup vs baseline: 1.0183x; 1.0183x over previous
//
#include <hip/hip_runtime.h>

// Problem constants
#define BB 4
#define CC 256
#define TT 8
#define HH 16
#define WW 16
#define LL 8
#define NO 8
#define DD 32
#define BT 32          // B*T
#define VV 2048        // H*W*L
#define KIN 512        // feat+pos channels for GEMM
#define EPS_ 1e-5f

typedef short bf16x8 __attribute__((ext_vector_type(8)));
typedef float f32x4 __attribute__((ext_vector_type(4)));
typedef float f32x2 __attribute__((ext_vector_type(2)));

static __device__ __forceinline__ float b2f(unsigned short u) {
    return __uint_as_float(((unsigned int)u) << 16);
}
static __device__ __forceinline__ float b2f_lo(unsigned int x) {
    return __uint_as_float(x << 16);
}
static __device__ __forceinline__ float b2f_hi(unsigned int x) {
    return __uint_as_float(x & 0xffff0000u);
}
static __device__ __forceinline__ unsigned short f2b(float f) {
    unsigned int x = __float_as_uint(f);
    unsigned int r = x + 0x7fffu + ((x >> 16) & 1u);   // RNE (finite values)
    return (unsigned short)(r >> 16);
}
static __device__ __forceinline__ unsigned int f2b_pk(float lo, float hi) {
    return (unsigned int)f2b(lo) | ((unsigned int)f2b(hi) << 16);
}
static __device__ __forceinline__ float sigm(float x) {
    return 1.0f / (1.0f + __expf(-x));
}
// async global->LDS, 16B per lane; LDS dest = wave-uniform base + lane*16
static __device__ __forceinline__ void glds16(const void* g, void* l) {
    __builtin_amdgcn_global_load_lds(
        (const __attribute__((address_space(1))) void*)g,
        (__attribute__((address_space(3))) void*)l, 16, 0, 0);
}
// lane-xor exchange routed off the DS pipe where possible:
// j=1,2 quad_perm DPP; j=8 row_ror:8 (==xor8 within 16); j=4,16 ds_swizzle; j=32 bpermute
static __device__ __forceinline__ int xsw(int x, int j) {
    switch (j) {
        case 1:  return __builtin_amdgcn_update_dpp(0, x, 0xB1, 0xF, 0xF, true);
        case 2:  return __builtin_amdgcn_update_dpp(0, x, 0x4E, 0xF, 0xF, true);
        case 8:  return __builtin_amdgcn_update_dpp(0, x, 0x128, 0xF, 0xF, true);
        case 4:  return __builtin_amdgcn_ds_swizzle(x, 0x101F);
        case 16: return __builtin_amdgcn_ds_swizzle(x, 0x401F);
        default: return __shfl_xor(x, 32);
    }
}

// ---------------------------------------------------------------------------
// K0: convert Wp[:, 0:512] -> bf16 A-matrix
// ---------------------------------------------------------------------------
__global__ __launch_bounds__(256) void k0_prep(const float* __restrict__ Wp,
                                               unsigned short* __restrict__ Wa) {
    int i = blockIdx.x * 256 + threadIdx.x;
    int o = i >> 9, k = i & 511;
    Wa[i] = f2b(Wp[o * 768 + k]);
}

// ---------------------------------------------------------------------------
// K1: streaming transpose feat/pos (B,C,T,v) -> srcT bf16 [n][v][512]
//     (unchanged from round-4 passing version)
// ---------------------------------------------------------------------------
__global__ __launch_bounds__(256) void k1_transpose(const float* __restrict__ features,
                                                    const float* __restrict__ pos,
                                                    unsigned short* __restrict__ srcT,
                                                    float* __restrict__ gpart) {
    const int vt  = blockIdx.x;         // 0..15 (128-v tile)
    const int ch  = blockIdx.y & 1;     // channel half 0..1
    const int arr = blockIdx.y >> 1;    // 0 = feat, 1 = pos
    const int n   = blockIdx.z;         // 0..31
    const int v0 = vt * 128;
    const int b = n >> 3, t = n & 7;
    const int tid = threadIdx.x;
    const int w = tid >> 6;             // wave 0..3 -> c range [w*32, w*32+32)
    const int lane = tid & 63;
    const int v16 = lane >> 2;          // 0..15 -> v group v16*4 (low half)
    const int cs  = lane & 3;           // 0..3

    __shared__ uint2 sg[128 * 33];      // granule g = v*33 + cq

    const float* src = arr ? pos : features;
    const size_t cb = ((size_t)(b * CC + ch * 128 + w * 32) * TT + t) * (size_t)VV
                      + v0 + v16 * 4;

    // 16 float4 loads in flight; per channel: vh=0 then vh=1 (+256B adjacent)
    float4 f[2][4][2];                  // [i][e][vh]
    #pragma unroll
    for (int i = 0; i < 2; ++i)
        #pragma unroll
        for (int e = 0; e < 4; ++e)
            #pragma unroll
            for (int vh = 0; vh < 2; ++vh)
                f[i][e][vh] = *(const float4*)(src + cb
                                + (size_t)(i * 16 + cs * 4 + e) * (TT * VV) + vh * 64);

    // pack channel quad -> uint2 (bf16 x4) per v, ds_write_b64 (conflict-free)
    #pragma unroll
    for (int i = 0; i < 2; ++i) {
        const int cq = w * 8 + i * 4 + cs;
        #pragma unroll
        for (int vh = 0; vh < 2; ++vh) {
            #pragma unroll
            for (int k = 0; k < 4; ++k) {
                const int v = vh * 64 + v16 * 4 + k;
                uint2 u;
                u.x = f2b_pk(((const float*)&f[i][0][vh])[k], ((const float*)&f[i][1][vh])[k]);
                u.y = f2b_pk(((const float*)&f[i][2][vh])[k], ((const float*)&f[i][3][vh])[k]);
                sg[v * 33 + cq] = u;
            }
        }
    }

    // fused per-channel feat sums (gpart) from registers: sum over 128 v
    if (arr == 0) {
        float part[2][4];
        #pragma unroll
        for (int i = 0; i < 2; ++i)
            #pragma unroll
            for (int e = 0; e < 4; ++e) {
                part[i][e] = f[i][e][0].x + f[i][e][0].y + f[i][e][0].z + f[i][e][0].w
                           + f[i][e][1].x + f[i][e][1].y + f[i][e][1].z + f[i][e][1].w;
                #pragma unroll
                for (int m = 4; m < 64; m <<= 1)
                    part[i][e] += __shfl_xor(part[i][e], m);
            }
        if (lane < 4) {   // v16 == 0, cs = lane
            float* gp = gpart + ((size_t)n * 16 + vt) * CC + ch * 128 + w * 32 + cs * 4;
            *(float4*)gp        = make_float4(part[0][0], part[0][1], part[0][2], part[0][3]);
            *(float4*)(gp + 16) = make_float4(part[1][0], part[1][1], part[1][2], part[1][3]);
        }
    }
    __syncthreads();

    // write-out: row v, 128 bf16 channels; 2x ds_read_b64 -> uint4 store (16B/lane)
    const int vh2 = tid >> 4;           // 0..15
    const int q   = tid & 15;           // 0..15 -> channels q*8..q*8+7
    unsigned short* ob = srcT + ((size_t)n * VV + v0) * KIN + arr * 256 + ch * 128 + q * 8;
    #pragma unroll
    for (int j = 0; j < 8; ++j) {
        const int v = j * 16 + vh2;
        uint2 lo = sg[v * 33 + q * 2];
        uint2 hi = sg[v * 33 + q * 2 + 1];
        uint4 o;
        o.x = lo.x; o.y = lo.y; o.z = hi.x; o.w = hi.y;
        *(uint4*)(ob + (size_t)v * KIN) = o;
    }
}

// ---------------------------------------------------------------------------
// K2: reduce gpart -> glob mean; gterm[n][o] = bp[o] + sum_c Wp[o][512+c]*mean[n][c]
// ---------------------------------------------------------------------------
__global__ __launch_bounds__(256) void k2_gterm(const float* __restrict__ gpart,
                                                const float* __restrict__ Wp,
                                                const float* __restrict__ bp,
                                                float* __restrict__ gterm) {
    const int n = blockIdx.x;
    const int o = threadIdx.x;          // channel index, then output index
    __shared__ float gl[CC];
    float s = 0.0f;
    const float* gp = gpart + (size_t)n * 16 * CC + o;
    #pragma unroll 8
    for (int vt = 0; vt < 16; ++vt) s += gp[vt * CC];
    gl[o] = s * (1.0f / (float)VV);
    __syncthreads();
    const float4* wrow = (const float4*)(Wp + (size_t)o * 768 + 512);
    const float4* g4 = (const float4*)gl;
    float acc = bp[o];
    #pragma unroll 8
    for (int c = 0; c < 64; ++c) {
        float4 w = wrow[c], g = g4[c];
        acc += w.x * g.x + w.y * g.y + w.z * g.z + w.w * g.w;
    }
    gterm[n * CC + o] = acc;
}

// ---------------------------------------------------------------------------
// K3: GEMM  projT[n][v][o] = relu( sum_k Wa[o][k]*srcT[n][v][k] + gterm[n][o] )
//     256x128 tile, 8 waves (4x2 of 64x64), 512 threads, 16x16x32 bf16 MFMA,
//     BK=32. Staged bytes/MFMA 192B (was 256B); half the blocks of round 4.
// ---------------------------------------------------------------------------
__global__ __launch_bounds__(512) void k3_gemm(const unsigned short* __restrict__ Wa,
                                               const unsigned short* __restrict__ srcT,
                                               const float* __restrict__ gterm,
                                               unsigned short* __restrict__ projT) {
    const int n  = blockIdx.x;   // batch 0..31
    const int nb = blockIdx.y;   // 0..15  (v block)
    const int tid = threadIdx.x;
    const int v0 = nb * 128;

    __shared__ short As[256 * 32];   // linear [row][k], 64B rows (16 KB)
    __shared__ short Bs[128 * 32];   // 8 KB

    const int w = tid >> 6;          // wave 0..7
    const int lane = tid & 63;
    const int wm = w >> 1;           // 0..3 -> o quarter
    const int wn = w & 1;            // 0..1 -> v half
    const int lr = lane & 15, lq = lane >> 4;

    f32x4 acc[4][4];
    #pragma unroll
    for (int i = 0; i < 4; ++i)
        #pragma unroll
        for (int j = 0; j < 4; ++j)
            acc[i][j] = (f32x4){0.f, 0.f, 0.f, 0.f};

    const int rsub = lane >> 2;          // 0..15
    const int ksub = (lane & 3) * 8;     // shorts
    // A: rows w*16+rsub (round 0) and 128 + w*16+rsub (round 1); 8 waves x 16 = 128 rows/round
    const unsigned short* agp = Wa   + (size_t)(w * 16 + rsub) * KIN + ksub;
    const unsigned short* bgp = srcT + ((size_t)n * VV + v0 + w * 16 + rsub) * KIN + ksub;
    short* alds0 = &As[(w * 16) * 32];          // wave-uniform bases
    short* alds1 = &As[(128 + w * 16) * 32];
    short* blds  = &Bs[(w * 16) * 32];

    for (int k0 = 0; k0 < KIN; k0 += 32) {
        __syncthreads();                       // prev tile fully consumed
        glds16(agp + k0,                     alds0);
        glds16(agp + k0 + (size_t)128 * KIN, alds1);
        glds16(bgp + k0,                     blds);
        __syncthreads();                       // vmcnt drained -> tiles ready

        bf16x8 af[4], bf[4];
        #pragma unroll
        for (int i = 0; i < 4; ++i)
            af[i] = *(const bf16x8*)&As[(wm * 64 + i * 16 + lr) * 32 + lq * 8];
        #pragma unroll
        for (int j = 0; j < 4; ++j)
            bf[j] = *(const bf16x8*)&Bs[(wn * 64 + j * 16 + lr) * 32 + lq * 8];
        #pragma unroll
        for (int i = 0; i < 4; ++i)
            #pragma unroll
            for (int j = 0; j < 4; ++j)
                acc[i][j] = __builtin_amdgcn_mfma_f32_16x16x32_bf16(af[i], bf[j], acc[i][j], 0, 0, 0);
    }

    // epilogue: C/D layout col=lane&15 (v), row=(lane>>4)*4+r (o)
    #pragma unroll
    for (int i = 0; i < 4; ++i) {
        const int og = wm * 64 + i * 16 + lq * 4;   // 0..255
        float4 g = *(const float4*)(gterm + n * CC + og);
        #pragma unroll
        for (int j = 0; j < 4; ++j) {
            const int vg = v0 + wn * 64 + j * 16 + lr;
            float x0 = fmaxf(acc[i][j][0] + g.x, 0.0f);
            float x1 = fmaxf(acc[i][j][1] + g.y, 0.0f);
            float x2 = fmaxf(acc[i][j][2] + g.z, 0.0f);
            float x3 = fmaxf(acc[i][j][3] + g.w, 0.0f);
            ushort4 st;
            st.x = f2b(x0); st.y = f2b(x1); st.z = f2b(x2); st.w = f2b(x3);
            *(ushort4*)&projT[((size_t)n * VV + vg) * CC + og] = st;
        }
    }
}

// ---------------------------------------------------------------------------
// K5 (fused K4+K5): per voxel, one wave.
//     Front-end: lane = head*8 + corner; octet MLP + corner eval -> (lin,w).
//     Dedup: PACKED-KEY bitonic sort (key2 = lin<<6 | lane, all distinct ->
//     single-word exchanges, weight recovered post-sort via one shfl),
//     segmented sum, compact, readlane gather.
//     res overlays projT: each wave reads exactly the row it overwrites. Safe.
// ---------------------------------------------------------------------------
__global__ __launch_bounds__(256) void k5_fused(const unsigned short* __restrict__ projT,
                                                const unsigned short* __restrict__ srcT,
                                                const float* __restrict__ Wo,
                                                const float* __restrict__ bo,
                                                const float* __restrict__ Ww,
                                                const float* __restrict__ bw,
                                                unsigned short* __restrict__ res) {
    __shared__ float sWo[96], sWd[32], sb[5];
    __shared__ int   sK[4 * 64];
    __shared__ float sW[4 * 64];
    const int tid = threadIdx.x;
    const int wid = tid >> 6;
    const int lane = tid & 63;
    if (tid < 96) sWo[tid] = Wo[tid];
    if (tid < 32) sWd[tid] = Ww[2 * tid + 1] - Ww[2 * tid];
    if (tid < 3)  sb[tid] = bo[tid];
    if (tid < 2)  sb[3 + tid] = bw[tid];
    __syncthreads();

    const int gv = blockIdx.x * 4 + wid;      // global voxel slot 0..65535
    const int n = gv >> 11;
    const int v = gv & 2047;

    // ---- fused K4 front-end ----
    const int hd = lane >> 3;                 // head 0..7
    const int s  = lane & 7;                  // corner 0..7 (dz=s>>2,dy=(s>>1)&1,dx=s&1)

    // lane reads 4 channels (8B); wave covers the full 512B projT row
    uint2 pr = *(const uint2*)(projT + ((size_t)n * VV + v) * CC + lane * 4);
    float t0 = b2f_lo(pr.x), t1 = b2f_hi(pr.x), t2 = b2f_lo(pr.y), t3 = b2f_hi(pr.y);
    const int d0 = s * 4;                     // channel-in-head of t0
    float o0 = t0 * sWo[3 * d0 + 0] + t1 * sWo[3 * d0 + 3] + t2 * sWo[3 * d0 + 6] + t3 * sWo[3 * d0 + 9];
    float o1 = t0 * sWo[3 * d0 + 1] + t1 * sWo[3 * d0 + 4] + t2 * sWo[3 * d0 + 7] + t3 * sWo[3 * d0 + 10];
    float o2 = t0 * sWo[3 * d0 + 2] + t1 * sWo[3 * d0 + 5] + t2 * sWo[3 * d0 + 8] + t3 * sWo[3 * d0 + 11];
    float zw = t0 * sWd[d0] + t1 * sWd[d0 + 1] + t2 * sWd[d0 + 2] + t3 * sWd[d0 + 3];
    // octet xor-reduce (lanes hd*8..hd*8+7)
    #pragma unroll
    for (int m = 1; m < 8; m <<= 1) {
        o0 += __shfl_xor(o0, m);
        o1 += __shfl_xor(o1, m);
        o2 += __shfl_xor(o2, m);
        zw += __shfl_xor(zw, m);
    }
    o0 += sb[0]; o1 += sb[1]; o2 += sb[2];
    const float wgt = sigm(zw + sb[4] - sb[3]);   // softmax(...)[...,1]

    const int h = v >> 7, wv_ = (v >> 3) & 15, l = v & 7;
    float ph = fminf(fmaxf(h   * (1.0f / 15.0f), EPS_), 1.0f - EPS_);
    float pw = fminf(fmaxf(wv_ * (1.0f / 15.0f), EPS_), 1.0f - EPS_);
    float pl = fminf(fmaxf(l   * (1.0f / 7.0f),  EPS_), 1.0f - EPS_);
    float sph = sigm(__logf(ph / (1.0f - ph)) + sigm(o0));
    float spw = sigm(__logf(pw / (1.0f - pw)) + sigm(o1));
    float spl = sigm(__logf(pl / (1.0f - pl)) + sigm(o2));
    float pixh = sph * 16.0f - 0.5f;
    float pixw = spw * 16.0f - 0.5f;
    float pixl = spl * 8.0f  - 0.5f;
    float flh = floorf(pixh), flw = floorf(pixw), fll = floorf(pixl);
    float fh = pixh - flh, fw = pixw - flw, fl = pixl - fll;
    const int dz = s >> 2, dy = (s >> 1) & 1, dx = s & 1;
    int iz = (int)flh + dz, iy = (int)flw + dy, ix = (int)fll + dx;
    float wt = (dz ? fh : 1.0f - fh) * (dy ? fw : 1.0f - fw) * (dx ? fl : 1.0f - fl) * wgt;
    bool valid = ((unsigned)iz < 16u) && ((unsigned)iy < 16u) && ((unsigned)ix < 8u);
    int lin = valid ? ((iz * 16 + iy) * 8 + ix) : 0;   // row index 0..2047
    float w0 = valid ? wt : 0.0f;

    // ---- dedup back-end: packed-key bitonic sort ----
    int key2 = (lin << 6) | lane;             // all 64 keys distinct
    #pragma unroll
    for (int k = 2; k <= 64; k <<= 1) {
        #pragma unroll
        for (int j = k >> 1; j > 0; j >>= 1) {
            int pk = xsw(key2, j);
            bool keepMin = (((lane & k) == 0) == ((lane & j) == 0));
            bool take = keepMin ? (pk < key2) : (pk > key2);
            if (take) key2 = pk;
        }
    }
    float w = __shfl(w0, key2 & 63);          // recover weight of sorted entry
    int klin = key2 >> 6;                     // sorted row index

    // segmented inclusive sum of w over equal-klin runs
    #pragma unroll
    for (int d = 1; d < 64; d <<= 1) {
        float tw = __shfl_up(w, d);
        int   tk = __shfl_up(klin, d);
        if (lane >= d && tk == klin) w += tw;
    }
    int nk = __shfl_down(klin, 1);
    bool tail = (lane == 63) || (nk != klin); // last lane of each run holds run total
    unsigned long long mask = __ballot(tail);
    int cnt = __popcll(mask);
    int cidx = __popcll(mask & ((1ull << lane) - 1ull));

    // compact unique (row byte offset, total w) into per-wave LDS; barriers load-bearing
    sK[wid * 64 + lane] = 0;
    sW[wid * 64 + lane] = 0.0f;
    __syncthreads();
    if (tail) { sK[wid * 64 + cidx] = klin << 10; sW[wid * 64 + cidx] = w; }
    __syncthreads();
    int ck = sK[wid * 64 + lane];
    float cw = sW[wid * 64 + lane];

    // gather unique rows: 64 lanes x 8B (4 channels each), 8 loads in flight
    const char* slabB = (const char*)srcT + (size_t)n * VV * KIN * 2 + lane * 8;
    f32x2 a01 = (f32x2){0.f, 0.f}, a23 = (f32x2){0.f, 0.f};
    const int iters = (cnt + 7) & ~7;
    #pragma unroll 1
    for (int e = 0; e < iters; e += 8) {
        uint2 f[8]; float wvv[8];
        #pragma unroll
        for (int u = 0; u < 8; ++u) {
            int rk = __builtin_amdgcn_readlane(ck, e + u);            // SGPR, no DS
            wvv[u] = __uint_as_float(
                        __builtin_amdgcn_readlane(__float_as_uint(cw), e + u));
            f[u] = *(const uint2*)(slabB + (unsigned)rk);
        }
        #pragma unroll
        for (int u = 0; u < 8; ++u) {
            a01 += wvv[u] * (f32x2){b2f_lo(f[u].x), b2f_hi(f[u].x)};  // v_pk_fma_f32
            a23 += wvv[u] * (f32x2){b2f_lo(f[u].y), b2f_hi(f[u].y)};
        }
    }

    uint2 st;
    st.x = f2b_pk(a01.x, a01.y);
    st.y = f2b_pk(a23.x, a23.y);
    *(uint2*)&res[((size_t)n * VV + v) * CC + lane * 4] = st;
}

// ---------------------------------------------------------------------------
// K6: out[b][c][t][v] = features[b][c][t][v] + res[n][v][c]   (LDS transpose)
//     c-tile 128: res reads as uint2 -> 256B segments.
// ---------------------------------------------------------------------------
__global__ __launch_bounds__(256) void k6_final(const float* __restrict__ features,
                                                const unsigned short* __restrict__ res,
                                                float* __restrict__ out) {
    const int n = blockIdx.x;            // 0..31
    const int c0 = blockIdx.y * 128;     // 0..1 -> c tile
    const int v0 = blockIdx.z * 64;      // 0..31 -> v tile
    const int b = n >> 3, t = n & 7;
    const int tid = threadIdx.x;

    __shared__ uint2 t6[64 * 33];        // [v][c-quad], pad 1

    // load: 8 passes x (8 rows x 32 uint2 = 128c)
    const int lr = tid >> 5;             // 0..7 row-sub
    const int cp = tid & 31;             // c-quad
    #pragma unroll
    for (int p = 0; p < 8; ++p) {
        const int r = p * 8 + lr;
        t6[r * 33 + cp] = *(const uint2*)&res[((size_t)n * VV + v0 + r) * CC + c0 + cp * 4];
    }
    __syncthreads();

    const unsigned short* t6s = (const unsigned short*)t6;
    const int tx = tid & 63;             // v within tile
    const int cl0 = tid >> 6;            // 0..3
    #pragma unroll 8
    for (int p = 0; p < 32; ++p) {
        const int cl = p * 4 + cl0;
        const int c = c0 + cl;
        size_t oidx = (((size_t)b * CC + c) * TT + t) * VV + v0 + tx;
        unsigned short val = t6s[(tx * 33 + (cl >> 2)) * 4 + (cl & 3)];
        out[oidx] = features[oidx] + b2f(val);
    }
}

// ---------------------------------------------------------------------------
extern "C" void kernel_launch(void* const* d_in, const int* in_sizes, int n_in,
                              void* d_out, int out_size, void* d_ws, size_t ws_size,
                              hipStream_t stream) {
    (void)in_sizes; (void)n_in; (void)out_size; (void)ws_size;
    const float* features = (const float*)d_in[0];
    const float* pos      = (const float*)d_in[1];
    const float* Wp       = (const float*)d_in[2];
    const float* bp       = (const float*)d_in[3];
    const float* Wo       = (const float*)d_in[4];
    const float* bo       = (const float*)d_in[5];
    const float* Ww       = (const float*)d_in[6];
    const float* bw       = (const float*)d_in[7];
    float* out = (float*)d_out;

    char* ws = (char*)d_ws;
    unsigned short* srcT  = (unsigned short*)ws;                   // 64 MiB: [32][2048][512] bf16
    unsigned short* Wa    = (unsigned short*)(ws + 67108864);      // 256 KiB
    float*          gterm = (float*)(ws + 67403776);               // 32 KiB
    unsigned short* projT = (unsigned short*)(ws + 67436544);      // 32 MiB: [32][2048][256] bf16
    float*          gpart = (float*)(ws + 100990976);              // 512 KiB: [32][16][256] f32
    unsigned short* res   = projT;                                 // overlay: each k5 wave reads
                                                                   // its projT row before overwriting

    k0_prep<<<512, 256, 0, stream>>>(Wp, Wa);
    k1_transpose<<<dim3(16, 4, 32), 256, 0, stream>>>(features, pos, srcT, gpart);
    k2_gterm<<<32, 256, 0, stream>>>(gpart, Wp, bp, gterm);
    k3_gemm<<<dim3(32, 16), 512, 0, stream>>>(Wa, srcT, gterm, projT);
    k5_fused<<<16384, 256, 0, stream>>>(projT, srcT, Wo, bo, Ww, bw, res);
    k6_final<<<dim3(32, 2, 32), 256, 0, stream>>>(features, res, out);
}